// Round 8
// baseline (835267.188 us; speedup 1.0000x reference)
//
#include <hip/hip_runtime.h>
#include <hip/hip_bf16.h>
#include <cstdint>

#define SENTW 0x7F7F7F7Fu   // float ~3.39e38; |h|<1 so never produced by LSTM

typedef unsigned uint4v __attribute__((ext_vector_type(4)));

// fast activations: v_exp_f32 (2^x) + v_rcp_f32, ~1-2 ulp each
__device__ __forceinline__ float fexp(float x){
  return __builtin_amdgcn_exp2f(x * 1.44269504088896341f);
}
__device__ __forceinline__ float sigf(float x){
  return __builtin_amdgcn_rcpf(1.f + fexp(-x));
}
__device__ __forceinline__ float tanh_fast(float x){
  return 1.f - 2.f*__builtin_amdgcn_rcpf(fexp(2.f*x) + 1.f);
}

// ======== PROBE 1: agent-scope (LLC) ping-pong. handoff = dur_us/16384 ========
__global__ __launch_bounds__(64) void k_pp_llc(unsigned* buf){
  if (threadIdx.x) return;
  unsigned* A = buf; unsigned* B = buf + 16;    // 64B apart
  const int N = 8192;
  if (blockIdx.x == 0){
    for (int i=1;i<=N;i++){
      __hip_atomic_store(A, (unsigned)i, __ATOMIC_RELAXED, __HIP_MEMORY_SCOPE_AGENT);
      while (__hip_atomic_load(B, __ATOMIC_RELAXED, __HIP_MEMORY_SCOPE_AGENT) != (unsigned)i) {}
    }
  } else {
    for (int i=1;i<=N;i++){
      while (__hip_atomic_load(A, __ATOMIC_RELAXED, __HIP_MEMORY_SCOPE_AGENT) != (unsigned)i) {}
      __hip_atomic_store(B, (unsigned)i, __ATOMIC_RELAXED, __HIP_MEMORY_SCOPE_AGENT);
    }
  }
}

// ======== PROBE 2: sc0-only (XCD-local L2) ping-pong between bid 0 and 8 ======
// If round-robin puts them on one XCD, completes fast (dur ~ RTT_L2*8192).
// Spin-capped: cannot hang even if placement assumption is wrong.
__global__ __launch_bounds__(64) void k_pp_l2(unsigned* buf){
  if (threadIdx.x) return;
  int role;
  if (blockIdx.x == 0) role = 0;
  else if (blockIdx.x == 8) role = 1;
  else return;
  unsigned* A = buf; unsigned* B = buf + 16;
  const int N = 4096;
  long cap = 8000000;    // bounded spin: worst case ~8M iters then give up
  if (role == 0){
    for (int i=1;i<=N && cap>0;i++){
      asm volatile("global_store_dword %0, %1, off sc0" :: "v"(A), "v"((unsigned)i) : "memory");
      unsigned v;
      do {
        asm volatile("global_load_dword %0, %1, off sc0\n\ts_waitcnt vmcnt(0)"
                     : "=v"(v) : "v"(B) : "memory");
      } while (v != (unsigned)i && --cap > 0);
    }
  } else {
    for (int i=1;i<=N && cap>0;i++){
      unsigned v;
      do {
        asm volatile("global_load_dword %0, %1, off sc0\n\ts_waitcnt vmcnt(0)"
                     : "=v"(v) : "v"(A) : "memory");
      } while (v != (unsigned)i && --cap > 0);
      asm volatile("global_store_dword %0, %1, off sc0" :: "v"(B), "v"((unsigned)i) : "memory");
    }
  }
}

// ---------------- embedding ----------------
__global__ __launch_bounds__(256) void k_embed(
    const int* __restrict__ x, const int* __restrict__ xp,
    const float* __restrict__ we, const float* __restrict__ pe,
    float* __restrict__ X)
{
  const int s = blockIdx.x, t = threadIdx.x;
  float4* xr = (float4*)(X + (size_t)s*1024);
  if (t < 224){
    const float4* wr = (const float4*)(we + (size_t)x[s]*896);
    xr[t] = wr[t];
  } else {
    const float4* pr = (const float4*)(pe + (size_t)xp[s]*128);
    xr[t] = pr[t-224];
  }
}

// ---------------- fp32 GEMM: C = A * B^T + bias + (*cadd) ----------------
__global__ __launch_bounds__(256,2) void k_gemm_abT(
    const float* __restrict__ A, const float* __restrict__ B, float* __restrict__ C,
    int M, int N, int K,
    const float* __restrict__ bias, const float* __restrict__ cadd)
{
  __shared__ float As[16][132];
  __shared__ float Bs[16][132];
  const int tid = threadIdx.x;
  const int m0 = blockIdx.y*128, n0 = blockIdx.x*128;
  const int r  = tid>>1, cq = tid&1;
  const int ty = tid>>4, tx = tid&15;

  float acc[8][8];
  #pragma unroll
  for (int i=0;i<8;i++)
    #pragma unroll
    for (int j=0;j<8;j++) acc[i][j]=0.f;

  for (int k0=0;k0<K;k0+=16){
    const float* ap = A + (size_t)(m0+r)*K + k0 + cq*8;
    const float* bp = B + (size_t)(n0+r)*K + k0 + cq*8;
    float4 a0 = *(const float4*)ap;
    float4 a1 = *(const float4*)(ap+4);
    float4 b0 = *(const float4*)bp;
    float4 b1 = *(const float4*)(bp+4);
    __syncthreads();
    As[cq*8+0][r]=a0.x; As[cq*8+1][r]=a0.y; As[cq*8+2][r]=a0.z; As[cq*8+3][r]=a0.w;
    As[cq*8+4][r]=a1.x; As[cq*8+5][r]=a1.y; As[cq*8+6][r]=a1.z; As[cq*8+7][r]=a1.w;
    Bs[cq*8+0][r]=b0.x; Bs[cq*8+1][r]=b0.y; Bs[cq*8+2][r]=b0.z; Bs[cq*8+3][r]=b0.w;
    Bs[cq*8+4][r]=b1.x; Bs[cq*8+5][r]=b1.y; Bs[cq*8+6][r]=b1.z; Bs[cq*8+7][r]=b1.w;
    __syncthreads();
    #pragma unroll
    for (int k=0;k<16;k++){
      float4 av0 = *(const float4*)&As[k][ty*8];
      float4 av1 = *(const float4*)&As[k][ty*8+4];
      float4 bv0 = *(const float4*)&Bs[k][tx*8];
      float4 bv1 = *(const float4*)&Bs[k][tx*8+4];
      float a[8]={av0.x,av0.y,av0.z,av0.w,av1.x,av1.y,av1.z,av1.w};
      float b[8]={bv0.x,bv0.y,bv0.z,bv0.w,bv1.x,bv1.y,bv1.z,bv1.w};
      #pragma unroll
      for (int i=0;i<8;i++)
        #pragma unroll
        for (int j=0;j<8;j++)
          acc[i][j] = fmaf(a[i],b[j],acc[i][j]);
    }
  }

  float cb = cadd ? *cadd : 0.f;
  float bv[8];
  if (bias){
    float4 t0 = *(const float4*)&bias[n0+tx*8];
    float4 t1 = *(const float4*)&bias[n0+tx*8+4];
    bv[0]=t0.x; bv[1]=t0.y; bv[2]=t0.z; bv[3]=t0.w;
    bv[4]=t1.x; bv[5]=t1.y; bv[6]=t1.z; bv[7]=t1.w;
  } else {
    #pragma unroll
    for (int j=0;j<8;j++) bv[j]=0.f;
  }
  #pragma unroll
  for (int i=0;i<8;i++){
    float* cp = C + (size_t)(m0+ty*8+i)*N + n0+tx*8;
    float4 o0, o1;
    o0.x=acc[i][0]+bv[0]+cb; o0.y=acc[i][1]+bv[1]+cb;
    o0.z=acc[i][2]+bv[2]+cb; o0.w=acc[i][3]+bv[3]+cb;
    o1.x=acc[i][4]+bv[4]+cb; o1.y=acc[i][5]+bv[5]+cb;
    o1.z=acc[i][6]+bv[6]+cb; o1.w=acc[i][7]+bv[7]+cb;
    *(float4*)cp = o0; *(float4*)(cp+4) = o1;
  }
}

// ---- merged head/dep GEMM ----
__global__ __launch_bounds__(256,2) void k_gemm_hd(
    const float* __restrict__ A,
    const float* __restrict__ Wh, const float* __restrict__ bh, float* __restrict__ Chead,
    const float* __restrict__ Wd, const float* __restrict__ bd, float* __restrict__ Cdep)
{
  __shared__ float As[16][132];
  __shared__ float Bs[16][132];
  const int tid = threadIdx.x;
  const int m0 = blockIdx.y*128;
  const int half = blockIdx.x >> 3;
  const int n0 = (blockIdx.x & 7)*128;
  const float* B    = half ? Wd : Wh;
  const float* bias = half ? bd : bh;
  float*       C    = half ? Cdep : Chead;
  const int r  = tid>>1, cq = tid&1;
  const int ty = tid>>4, tx = tid&15;

  float acc[8][8];
  #pragma unroll
  for (int i=0;i<8;i++)
    #pragma unroll
    for (int j=0;j<8;j++) acc[i][j]=0.f;

  for (int k0=0;k0<1024;k0+=16){
    const float* ap = A + (size_t)(m0+r)*1024 + k0 + cq*8;
    const float* bp = B + (size_t)(n0+r)*1024 + k0 + cq*8;
    float4 a0 = *(const float4*)ap;
    float4 a1 = *(const float4*)(ap+4);
    float4 b0 = *(const float4*)bp;
    float4 b1 = *(const float4*)(bp+4);
    __syncthreads();
    As[cq*8+0][r]=a0.x; As[cq*8+1][r]=a0.y; As[cq*8+2][r]=a0.z; As[cq*8+3][r]=a0.w;
    As[cq*8+4][r]=a1.x; As[cq*8+5][r]=a1.y; As[cq*8+6][r]=a1.z; As[cq*8+7][r]=a1.w;
    Bs[cq*8+0][r]=b0.x; Bs[cq*8+1][r]=b0.y; Bs[cq*8+2][r]=b0.z; Bs[cq*8+3][r]=b0.w;
    Bs[cq*8+4][r]=b1.x; Bs[cq*8+5][r]=b1.y; Bs[cq*8+6][r]=b1.z; Bs[cq*8+7][r]=b1.w;
    __syncthreads();
    #pragma unroll
    for (int k=0;k<16;k++){
      float4 av0 = *(const float4*)&As[k][ty*8];
      float4 av1 = *(const float4*)&As[k][ty*8+4];
      float4 bv0 = *(const float4*)&Bs[k][tx*8];
      float4 bv1 = *(const float4*)&Bs[k][tx*8+4];
      float a[8]={av0.x,av0.y,av0.z,av0.w,av1.x,av1.y,av1.z,av1.w};
      float b[8]={bv0.x,bv0.y,bv0.z,bv0.w,bv1.x,bv1.y,bv1.z,bv1.w};
      #pragma unroll
      for (int i=0;i<8;i++)
        #pragma unroll
        for (int j=0;j<8;j++)
          acc[i][j] = fmaf(a[i],b[j],acc[i][j]);
    }
  }

  float4 t0 = *(const float4*)&bias[n0+tx*8];
  float4 t1 = *(const float4*)&bias[n0+tx*8+4];
  float bv[8] = {t0.x,t0.y,t0.z,t0.w,t1.x,t1.y,t1.z,t1.w};
  #pragma unroll
  for (int i=0;i<8;i++){
    float* cp = C + (size_t)(m0+ty*8+i)*1024 + n0+tx*8;
    float4 o0, o1;
    o0.x=acc[i][0]+bv[0]; o0.y=acc[i][1]+bv[1];
    o0.z=acc[i][2]+bv[2]; o0.w=acc[i][3]+bv[3];
    o1.x=acc[i][4]+bv[4]; o1.y=acc[i][5]+bv[5];
    o1.z=acc[i][6]+bv[6]; o1.w=acc[i][7]+bv[7];
    *(float4*)cp = o0; *(float4*)(cp+4) = o1;
  }
}

// ---------------- LSTM scan (R6 structure, s_sleep removed) ----------------
__global__ __launch_bounds__(512,1) void k_lstm_scan(
    const float* __restrict__ pre,   // [1024][4096]: dir*2048 + gate*512 + unit
    const float* __restrict__ Whh,   // [2][2048][512] (this layer)
    float* __restrict__ out)         // [1024][1024]; fwd cols 0..511, bwd 512..1023
{
  const int wg  = blockIdx.x;
  const int dir = wg >> 5;
  const int w   = wg & 31;
  const int tid = threadIdx.x;
  const int kc  = tid & 7;
  const int rl  = tid >> 3;
  const int gate= rl & 3;
  const int ul  = rl >> 2;
  const int unit= w*16 + ul;
  const int grow= gate*512 + unit;

  __shared__ float hsh[2][544];

  float wreg[64];
  {
    const float* wp = Whh + ((size_t)dir*2048 + grow)*512 + kc*64;
    #pragma unroll
    for (int j=0;j<16;j++){
      float4 q = *(const float4*)(wp + 4*j);
      wreg[4*j+0]=q.x; wreg[4*j+1]=q.y; wreg[4*j+2]=q.z; wreg[4*j+3]=q.w;
    }
  }

  unsigned* ob = (unsigned*)out;
  const float* prebase = pre + (size_t)dir*2048 + grow;
  float c = 0.f;
  const int base = (tid & 32);

  for (int t=0;t<1024;t++){
    const int s  = dir ? (1023 - t) : t;
    const int sp = dir ? (s + 1) : (s - 1);

    float preval = 0.f;
    if (kc==0) preval = prebase[(size_t)s*4096];

    float accv = 0.f;
    if (t > 0){
      if (tid < 64){
        const unsigned* hp = ob + (size_t)sp*1024 + dir*512 + 8*tid;
        uint4v a, b;
        for(;;){
          asm volatile(
            "global_load_dwordx4 %0, %2, off sc0 sc1\n\t"
            "global_load_dwordx4 %1, %3, off sc0 sc1\n\t"
            "s_waitcnt vmcnt(0)"
            : "=&v"(a), "=&v"(b)
            : "v"(hp), "v"(hp+4)
            : "memory");
          unsigned ok = 1u;
          ok &= (unsigned)(a.x!=SENTW) & (unsigned)(a.y!=SENTW);
          ok &= (unsigned)(a.z!=SENTW) & (unsigned)(a.w!=SENTW);
          ok &= (unsigned)(b.x!=SENTW) & (unsigned)(b.y!=SENTW);
          ok &= (unsigned)(b.z!=SENTW) & (unsigned)(b.w!=SENTW);
          if (ok) break;
        }
        float* hb = hsh[t & 1];
        const int sb = (tid>>3)*68 + (tid&7)*8;
        hb[sb+0]=__uint_as_float(a.x); hb[sb+1]=__uint_as_float(a.y);
        hb[sb+2]=__uint_as_float(a.z); hb[sb+3]=__uint_as_float(a.w);
        hb[sb+4]=__uint_as_float(b.x); hb[sb+5]=__uint_as_float(b.y);
        hb[sb+6]=__uint_as_float(b.z); hb[sb+7]=__uint_as_float(b.w);
      }
      __syncthreads();

      const float* hv = hsh[t & 1] + kc*68;
      float p0=0.f,p1=0.f,p2=0.f,p3=0.f;
      #pragma unroll
      for (int j=0;j<16;j++){
        float4 q = *(const float4*)(hv + 4*j);
        p0 = fmaf(wreg[4*j+0], q.x, p0);
        p1 = fmaf(wreg[4*j+1], q.y, p1);
        p2 = fmaf(wreg[4*j+2], q.z, p2);
        p3 = fmaf(wreg[4*j+3], q.w, p3);
      }
      accv = (p0+p1)+(p2+p3);
      accv += __shfl_xor(accv, 1);
      accv += __shfl_xor(accv, 2);
      accv += __shfl_xor(accv, 4);
    }
    float act = 0.f;
    if (kc==0){
      float g = accv + preval;
      act = (gate==2) ? tanh_fast(g) : sigf(g);
    }
    float ai = __shfl(act, base+0);
    float af = __shfl(act, base+8);
    float ag = __shfl(act, base+16);
    float ao = __shfl(act, base+24);
    float h = 0.f;
    if ((tid&31)==0){
      c = af*c + ai*ag;
      h = ao*tanh_fast(c);
    }
    float h2 = __shfl(h, 32);
    if ((tid&63)==0){
      unsigned long long pv =
          ((unsigned long long)__float_as_uint(h2) << 32) | __float_as_uint(h);
      unsigned long long* dst =
          (unsigned long long*)(ob + (size_t)s*1024 + dir*512) + (w*8 + (tid>>6));
      (void)__hip_atomic_exchange(dst, pv, __ATOMIC_RELAXED, __HIP_MEMORY_SCOPE_AGENT);
    }
  }
}

// ---------------- row softmax, in place ----------------
__global__ __launch_bounds__(256) void k_softmax(float* __restrict__ P){
  __shared__ float redm[4], reds[4];
  const int i = blockIdx.x, tid = threadIdx.x;
  float4 v = *(float4*)&P[(size_t)i*1024 + tid*4];
  float m = fmaxf(fmaxf(v.x,v.y), fmaxf(v.z,v.w));
  #pragma unroll
  for (int o=32;o;o>>=1) m = fmaxf(m, __shfl_xor(m,o));
  if ((tid&63)==0) redm[tid>>6] = m;
  __syncthreads();
  m = fmaxf(fmaxf(redm[0],redm[1]), fmaxf(redm[2],redm[3]));
  v.x = expf(v.x-m); v.y = expf(v.y-m); v.z = expf(v.z-m); v.w = expf(v.w-m);
  float su = v.x+v.y+v.z+v.w;
  #pragma unroll
  for (int o=32;o;o>>=1) su += __shfl_xor(su,o);
  if ((tid&63)==0) reds[tid>>6] = su;
  __syncthreads();
  su = reds[0]+reds[1]+reds[2]+reds[3];
  float inv = 1.f/su;
  v.x*=inv; v.y*=inv; v.z*=inv; v.w*=inv;
  *(float4*)&P[(size_t)i*1024 + tid*4] = v;
}

extern "C" void kernel_launch(void* const* d_in, const int* in_sizes, int n_in,
                              void* d_out, int out_size, void* d_ws, size_t ws_size,
                              hipStream_t stream)
{
  const int*   x    = (const int*)d_in[0];
  const int*   xp   = (const int*)d_in[1];
  const float* we   = (const float*)d_in[2];
  const float* pe   = (const float*)d_in[3];
  const float* Wih  = (const float*)d_in[4];
  const float* Whh  = (const float*)d_in[5];
  const float* bl   = (const float*)d_in[6];
  const float* Wh   = (const float*)d_in[7];
  const float* bh   = (const float*)d_in[8];
  const float* Wd   = (const float*)d_in[9];
  const float* bd   = (const float*)d_in[10];
  const float* Wbi  = (const float*)d_in[11];
  const float* bbi  = (const float*)d_in[12];
  float* outp = (float*)d_out;

  char* ws = (char*)d_ws;
  float* X0   = (float*)(ws);                   // [0,4M)
  float* pre  = (float*)(ws + ((size_t)4<<20)); // [4M,20M)
  float* out0 = (float*)(ws + ((size_t)20<<20));// [20M,24M)
  float* out1 = (float*)(ws + ((size_t)24<<20));// [24M,28M)
  float* head = (float*)(ws);                   // reuse [0,4M)
  float* dep  = (float*)(ws + ((size_t)4<<20)); // reuse [4M,8M)
  float* Ubuf = (float*)(ws + ((size_t)8<<20)); // reuse [8M,12M)
  unsigned* pp = (unsigned*)(ws + ((size_t)12<<20)); // probe scratch (inside pre; probes run first)

  // probes (instrumented round): zero probe lines, then run both ping-pongs
  hipMemsetAsync(pp, 0, 512, stream);
  k_pp_llc<<<2, 64, 0, stream>>>(pp);
  k_pp_l2 <<<9, 64, 0, stream>>>(pp + 64);

  // sentinel-init the scan outputs
  hipMemsetAsync(out0, 0x7F, (size_t)8<<20, stream);

  dim3 blk(256);
  k_embed<<<1024, blk, 0, stream>>>(x, xp, we, pe, X0);

  k_gemm_abT<<<dim3(32,8), blk, 0, stream>>>(X0, Wih, pre, 1024, 4096, 1024, bl, nullptr);
  k_lstm_scan<<<64, dim3(512), 0, stream>>>(pre, Whh, out0);

  k_gemm_abT<<<dim3(32,8), blk, 0, stream>>>(out0, Wih + (size_t)4096*1024, pre,
                                             1024, 4096, 1024, bl + 4096, nullptr);
  k_lstm_scan<<<64, dim3(512), 0, stream>>>(pre, Whh + (size_t)2*2048*512, out1);

  k_gemm_hd <<<dim3(16,8), blk, 0, stream>>>(out1, Wh, bh, head, Wd, bd, dep);
  k_gemm_abT<<<dim3(8,8), blk, 0, stream>>>(dep,  Wbi, Ubuf,1024, 1024, 1024, nullptr, nullptr);
  k_gemm_abT<<<dim3(8,8), blk, 0, stream>>>(head, Ubuf, outp,1024, 1024, 1024, nullptr, bbi);

  k_softmax<<<1024, blk, 0, stream>>>(outp);
}

// Round 9
// 6826.638 us; speedup vs baseline: 122.3541x; 122.3541x over previous
//
#include <hip/hip_runtime.h>
#include <hip/hip_bf16.h>
#include <cstdint>

#define SENTW 0x7F7F7F7Fu   // float ~3.39e38; |h|<1 so never produced by LSTM
#define SCAN_WGS 64
#define HEAT_WGS 48

typedef unsigned uint4v __attribute__((ext_vector_type(4)));

// fast activations: v_exp_f32 (2^x) + v_rcp_f32, ~1-2 ulp each
__device__ __forceinline__ float fexp(float x){
  return __builtin_amdgcn_exp2f(x * 1.44269504088896341f);
}
__device__ __forceinline__ float sigf(float x){
  return __builtin_amdgcn_rcpf(1.f + fexp(-x));
}
__device__ __forceinline__ float tanh_fast(float x){
  return 1.f - 2.f*__builtin_amdgcn_rcpf(fexp(2.f*x) + 1.f);
}

// ---------------- embedding ----------------
__global__ __launch_bounds__(256) void k_embed(
    const int* __restrict__ x, const int* __restrict__ xp,
    const float* __restrict__ we, const float* __restrict__ pe,
    float* __restrict__ X)
{
  const int s = blockIdx.x, t = threadIdx.x;
  float4* xr = (float4*)(X + (size_t)s*1024);
  if (t < 224){
    const float4* wr = (const float4*)(we + (size_t)x[s]*896);
    xr[t] = wr[t];
  } else {
    const float4* pr = (const float4*)(pe + (size_t)xp[s]*128);
    xr[t] = pr[t-224];
  }
}

// ---------------- fp32 GEMM: C = A * B^T + bias + (*cadd) ----------------
__global__ __launch_bounds__(256,2) void k_gemm_abT(
    const float* __restrict__ A, const float* __restrict__ B, float* __restrict__ C,
    int M, int N, int K,
    const float* __restrict__ bias, const float* __restrict__ cadd)
{
  __shared__ float As[16][132];
  __shared__ float Bs[16][132];
  const int tid = threadIdx.x;
  const int m0 = blockIdx.y*128, n0 = blockIdx.x*128;
  const int r  = tid>>1, cq = tid&1;
  const int ty = tid>>4, tx = tid&15;

  float acc[8][8];
  #pragma unroll
  for (int i=0;i<8;i++)
    #pragma unroll
    for (int j=0;j<8;j++) acc[i][j]=0.f;

  for (int k0=0;k0<K;k0+=16){
    const float* ap = A + (size_t)(m0+r)*K + k0 + cq*8;
    const float* bp = B + (size_t)(n0+r)*K + k0 + cq*8;
    float4 a0 = *(const float4*)ap;
    float4 a1 = *(const float4*)(ap+4);
    float4 b0 = *(const float4*)bp;
    float4 b1 = *(const float4*)(bp+4);
    __syncthreads();
    As[cq*8+0][r]=a0.x; As[cq*8+1][r]=a0.y; As[cq*8+2][r]=a0.z; As[cq*8+3][r]=a0.w;
    As[cq*8+4][r]=a1.x; As[cq*8+5][r]=a1.y; As[cq*8+6][r]=a1.z; As[cq*8+7][r]=a1.w;
    Bs[cq*8+0][r]=b0.x; Bs[cq*8+1][r]=b0.y; Bs[cq*8+2][r]=b0.z; Bs[cq*8+3][r]=b0.w;
    Bs[cq*8+4][r]=b1.x; Bs[cq*8+5][r]=b1.y; Bs[cq*8+6][r]=b1.z; Bs[cq*8+7][r]=b1.w;
    __syncthreads();
    #pragma unroll
    for (int k=0;k<16;k++){
      float4 av0 = *(const float4*)&As[k][ty*8];
      float4 av1 = *(const float4*)&As[k][ty*8+4];
      float4 bv0 = *(const float4*)&Bs[k][tx*8];
      float4 bv1 = *(const float4*)&Bs[k][tx*8+4];
      float a[8]={av0.x,av0.y,av0.z,av0.w,av1.x,av1.y,av1.z,av1.w};
      float b[8]={bv0.x,bv0.y,bv0.z,bv0.w,bv1.x,bv1.y,bv1.z,bv1.w};
      #pragma unroll
      for (int i=0;i<8;i++)
        #pragma unroll
        for (int j=0;j<8;j++)
          acc[i][j] = fmaf(a[i],b[j],acc[i][j]);
    }
  }

  float cb = cadd ? *cadd : 0.f;
  float bv[8];
  if (bias){
    float4 t0 = *(const float4*)&bias[n0+tx*8];
    float4 t1 = *(const float4*)&bias[n0+tx*8+4];
    bv[0]=t0.x; bv[1]=t0.y; bv[2]=t0.z; bv[3]=t0.w;
    bv[4]=t1.x; bv[5]=t1.y; bv[6]=t1.z; bv[7]=t1.w;
  } else {
    #pragma unroll
    for (int j=0;j<8;j++) bv[j]=0.f;
  }
  #pragma unroll
  for (int i=0;i<8;i++){
    float* cp = C + (size_t)(m0+ty*8+i)*N + n0+tx*8;
    float4 o0, o1;
    o0.x=acc[i][0]+bv[0]+cb; o0.y=acc[i][1]+bv[1]+cb;
    o0.z=acc[i][2]+bv[2]+cb; o0.w=acc[i][3]+bv[3]+cb;
    o1.x=acc[i][4]+bv[4]+cb; o1.y=acc[i][5]+bv[5]+cb;
    o1.z=acc[i][6]+bv[6]+cb; o1.w=acc[i][7]+bv[7]+cb;
    *(float4*)cp = o0; *(float4*)(cp+4) = o1;
  }
}

// ---- merged head/dep GEMM ----
__global__ __launch_bounds__(256,2) void k_gemm_hd(
    const float* __restrict__ A,
    const float* __restrict__ Wh, const float* __restrict__ bh, float* __restrict__ Chead,
    const float* __restrict__ Wd, const float* __restrict__ bd, float* __restrict__ Cdep)
{
  __shared__ float As[16][132];
  __shared__ float Bs[16][132];
  const int tid = threadIdx.x;
  const int m0 = blockIdx.y*128;
  const int half = blockIdx.x >> 3;
  const int n0 = (blockIdx.x & 7)*128;
  const float* B    = half ? Wd : Wh;
  const float* bias = half ? bd : bh;
  float*       C    = half ? Cdep : Chead;
  const int r  = tid>>1, cq = tid&1;
  const int ty = tid>>4, tx = tid&15;

  float acc[8][8];
  #pragma unroll
  for (int i=0;i<8;i++)
    #pragma unroll
    for (int j=0;j<8;j++) acc[i][j]=0.f;

  for (int k0=0;k0<1024;k0+=16){
    const float* ap = A + (size_t)(m0+r)*1024 + k0 + cq*8;
    const float* bp = B + (size_t)(n0+r)*1024 + k0 + cq*8;
    float4 a0 = *(const float4*)ap;
    float4 a1 = *(const float4*)(ap+4);
    float4 b0 = *(const float4*)bp;
    float4 b1 = *(const float4*)(bp+4);
    __syncthreads();
    As[cq*8+0][r]=a0.x; As[cq*8+1][r]=a0.y; As[cq*8+2][r]=a0.z; As[cq*8+3][r]=a0.w;
    As[cq*8+4][r]=a1.x; As[cq*8+5][r]=a1.y; As[cq*8+6][r]=a1.z; As[cq*8+7][r]=a1.w;
    Bs[cq*8+0][r]=b0.x; Bs[cq*8+1][r]=b0.y; Bs[cq*8+2][r]=b0.z; Bs[cq*8+3][r]=b0.w;
    Bs[cq*8+4][r]=b1.x; Bs[cq*8+5][r]=b1.y; Bs[cq*8+6][r]=b1.z; Bs[cq*8+7][r]=b1.w;
    __syncthreads();
    #pragma unroll
    for (int k=0;k<16;k++){
      float4 av0 = *(const float4*)&As[k][ty*8];
      float4 av1 = *(const float4*)&As[k][ty*8+4];
      float4 bv0 = *(const float4*)&Bs[k][tx*8];
      float4 bv1 = *(const float4*)&Bs[k][tx*8+4];
      float a[8]={av0.x,av0.y,av0.z,av0.w,av1.x,av1.y,av1.z,av1.w};
      float b[8]={bv0.x,bv0.y,bv0.z,bv0.w,bv1.x,bv1.y,bv1.z,bv1.w};
      #pragma unroll
      for (int i=0;i<8;i++)
        #pragma unroll
        for (int j=0;j<8;j++)
          acc[i][j] = fmaf(a[i],b[j],acc[i][j]);
    }
  }

  float4 t0 = *(const float4*)&bias[n0+tx*8];
  float4 t1 = *(const float4*)&bias[n0+tx*8+4];
  float bv[8] = {t0.x,t0.y,t0.z,t0.w,t1.x,t1.y,t1.z,t1.w};
  #pragma unroll
  for (int i=0;i<8;i++){
    float* cp = C + (size_t)(m0+ty*8+i)*1024 + n0+tx*8;
    float4 o0, o1;
    o0.x=acc[i][0]+bv[0]; o0.y=acc[i][1]+bv[1];
    o0.z=acc[i][2]+bv[2]; o0.w=acc[i][3]+bv[3];
    o1.x=acc[i][4]+bv[4]; o1.y=acc[i][5]+bv[5];
    o1.z=acc[i][6]+bv[6]; o1.w=acc[i][7]+bv[7];
    *(float4*)cp = o0; *(float4*)(cp+4) = o1;
  }
}

// ---------------- LSTM scan + fabric heater ----------------
// Blocks 0..63: R7 scan (unchanged). Blocks 64..111: heater — stream-read
// 32MB (Wih) to keep LLC/fabric clocks boosted during the latency-bound
// scan (DVFS hypothesis test). Heater exits by watching the scan's own
// final-step sentinel slots; bounded pass count so it can never hang.
__global__ __launch_bounds__(512,1) void k_lstm_scan(
    const float* __restrict__ pre,   // [1024][4096]: dir*2048 + gate*512 + unit
    const float* __restrict__ Whh,   // [2][2048][512] (this layer)
    float* __restrict__ out,         // [1024][1024]; fwd cols 0..511, bwd 512..1023
    const float* __restrict__ heat)  // 32MB read-only stream region
{
  const int tid = threadIdx.x;

  if (blockIdx.x >= SCAN_WGS){
    // ---- heater ----
    const unsigned* ob = (const unsigned*)out;
    const unsigned* fin0 = ob + ((size_t)1023<<10);  // fwd unit 0 @ s=1023 (last fwd publish)
    const unsigned* fin1 = ob + 512;                 // bwd unit 512 @ s=0  (last bwd publish)
    const float4* h4 = (const float4*)heat;
    const int stride = HEAT_WGS*512;
    const int n4 = (32<<20)/16;                      // 2M float4
    float acc = 0.f;
    for (int pass=0; pass<50000; ++pass){
      unsigned a = __hip_atomic_load(fin0, __ATOMIC_RELAXED, __HIP_MEMORY_SCOPE_AGENT);
      unsigned b = __hip_atomic_load(fin1, __ATOMIC_RELAXED, __HIP_MEMORY_SCOPE_AGENT);
      if (a != SENTW && b != SENTW) break;
      for (int i = (blockIdx.x-SCAN_WGS)*512 + tid; i < n4; i += stride){
        float4 v = h4[i];
        acc += v.x + v.y + v.z + v.w;
      }
    }
    asm volatile("" :: "v"(acc));   // keep the reads live (rule #17)
    return;
  }

  // ---- scan (identical to R7) ----
  const int wg  = blockIdx.x;
  const int dir = wg >> 5;
  const int w   = wg & 31;
  const int kc  = tid & 7;
  const int rl  = tid >> 3;
  const int gate= rl & 3;
  const int ul  = rl >> 2;
  const int unit= w*16 + ul;
  const int grow= gate*512 + unit;

  __shared__ float hsh[2][544];

  float wreg[64];
  {
    const float* wp = Whh + ((size_t)dir*2048 + grow)*512 + kc*64;
    #pragma unroll
    for (int j=0;j<16;j++){
      float4 q = *(const float4*)(wp + 4*j);
      wreg[4*j+0]=q.x; wreg[4*j+1]=q.y; wreg[4*j+2]=q.z; wreg[4*j+3]=q.w;
    }
  }

  unsigned* ob = (unsigned*)out;
  const float* prebase = pre + (size_t)dir*2048 + grow;
  float c = 0.f;
  const int base = (tid & 32);

  for (int t=0;t<1024;t++){
    const int s  = dir ? (1023 - t) : t;
    const int sp = dir ? (s + 1) : (s - 1);

    float preval = 0.f;
    if (kc==0) preval = prebase[(size_t)s*4096];

    float accv = 0.f;
    if (t > 0){
      if (tid < 64){
        const unsigned* hp = ob + (size_t)sp*1024 + dir*512 + 8*tid;
        uint4v a, b;
        for(;;){
          asm volatile(
            "global_load_dwordx4 %0, %2, off sc0 sc1\n\t"
            "global_load_dwordx4 %1, %3, off sc0 sc1\n\t"
            "s_waitcnt vmcnt(0)"
            : "=&v"(a), "=&v"(b)
            : "v"(hp), "v"(hp+4)
            : "memory");
          unsigned ok = 1u;
          ok &= (unsigned)(a.x!=SENTW) & (unsigned)(a.y!=SENTW);
          ok &= (unsigned)(a.z!=SENTW) & (unsigned)(a.w!=SENTW);
          ok &= (unsigned)(b.x!=SENTW) & (unsigned)(b.y!=SENTW);
          ok &= (unsigned)(b.z!=SENTW) & (unsigned)(b.w!=SENTW);
          if (ok) break;
        }
        float* hb = hsh[t & 1];
        const int sb = (tid>>3)*68 + (tid&7)*8;
        hb[sb+0]=__uint_as_float(a.x); hb[sb+1]=__uint_as_float(a.y);
        hb[sb+2]=__uint_as_float(a.z); hb[sb+3]=__uint_as_float(a.w);
        hb[sb+4]=__uint_as_float(b.x); hb[sb+5]=__uint_as_float(b.y);
        hb[sb+6]=__uint_as_float(b.z); hb[sb+7]=__uint_as_float(b.w);
      }
      __syncthreads();

      const float* hv = hsh[t & 1] + kc*68;
      float p0=0.f,p1=0.f,p2=0.f,p3=0.f;
      #pragma unroll
      for (int j=0;j<16;j++){
        float4 q = *(const float4*)(hv + 4*j);
        p0 = fmaf(wreg[4*j+0], q.x, p0);
        p1 = fmaf(wreg[4*j+1], q.y, p1);
        p2 = fmaf(wreg[4*j+2], q.z, p2);
        p3 = fmaf(wreg[4*j+3], q.w, p3);
      }
      accv = (p0+p1)+(p2+p3);
      accv += __shfl_xor(accv, 1);
      accv += __shfl_xor(accv, 2);
      accv += __shfl_xor(accv, 4);
    }
    float act = 0.f;
    if (kc==0){
      float g = accv + preval;
      act = (gate==2) ? tanh_fast(g) : sigf(g);
    }
    float ai = __shfl(act, base+0);
    float af = __shfl(act, base+8);
    float ag = __shfl(act, base+16);
    float ao = __shfl(act, base+24);
    float h = 0.f;
    if ((tid&31)==0){
      c = af*c + ai*ag;
      h = ao*tanh_fast(c);
    }
    float h2 = __shfl(h, 32);
    if ((tid&63)==0){
      unsigned long long pv =
          ((unsigned long long)__float_as_uint(h2) << 32) | __float_as_uint(h);
      unsigned long long* dst =
          (unsigned long long*)(ob + (size_t)s*1024 + dir*512) + (w*8 + (tid>>6));
      (void)__hip_atomic_exchange(dst, pv, __ATOMIC_RELAXED, __HIP_MEMORY_SCOPE_AGENT);
    }
  }
}

// ---------------- row softmax, in place ----------------
__global__ __launch_bounds__(256) void k_softmax(float* __restrict__ P){
  __shared__ float redm[4], reds[4];
  const int i = blockIdx.x, tid = threadIdx.x;
  float4 v = *(float4*)&P[(size_t)i*1024 + tid*4];
  float m = fmaxf(fmaxf(v.x,v.y), fmaxf(v.z,v.w));
  #pragma unroll
  for (int o=32;o;o>>=1) m = fmaxf(m, __shfl_xor(m,o));
  if ((tid&63)==0) redm[tid>>6] = m;
  __syncthreads();
  m = fmaxf(fmaxf(redm[0],redm[1]), fmaxf(redm[2],redm[3]));
  v.x = expf(v.x-m); v.y = expf(v.y-m); v.z = expf(v.z-m); v.w = expf(v.w-m);
  float su = v.x+v.y+v.z+v.w;
  #pragma unroll
  for (int o=32;o;o>>=1) su += __shfl_xor(su,o);
  if ((tid&63)==0) reds[tid>>6] = su;
  __syncthreads();
  su = reds[0]+reds[1]+reds[2]+reds[3];
  float inv = 1.f/su;
  v.x*=inv; v.y*=inv; v.z*=inv; v.w*=inv;
  *(float4*)&P[(size_t)i*1024 + tid*4] = v;
}

extern "C" void kernel_launch(void* const* d_in, const int* in_sizes, int n_in,
                              void* d_out, int out_size, void* d_ws, size_t ws_size,
                              hipStream_t stream)
{
  const int*   x    = (const int*)d_in[0];
  const int*   xp   = (const int*)d_in[1];
  const float* we   = (const float*)d_in[2];
  const float* pe   = (const float*)d_in[3];
  const float* Wih  = (const float*)d_in[4];
  const float* Whh  = (const float*)d_in[5];
  const float* bl   = (const float*)d_in[6];
  const float* Wh   = (const float*)d_in[7];
  const float* bh   = (const float*)d_in[8];
  const float* Wd   = (const float*)d_in[9];
  const float* bd   = (const float*)d_in[10];
  const float* Wbi  = (const float*)d_in[11];
  const float* bbi  = (const float*)d_in[12];
  float* outp = (float*)d_out;

  char* ws = (char*)d_ws;
  float* X0   = (float*)(ws);                   // [0,4M)
  float* pre  = (float*)(ws + ((size_t)4<<20)); // [4M,20M)
  float* out0 = (float*)(ws + ((size_t)20<<20));// [20M,24M)
  float* out1 = (float*)(ws + ((size_t)24<<20));// [24M,28M)
  float* head = (float*)(ws);                   // reuse [0,4M)
  float* dep  = (float*)(ws + ((size_t)4<<20)); // reuse [4M,8M)
  float* Ubuf = (float*)(ws + ((size_t)8<<20)); // reuse [8M,12M)

  // sentinel-init the scan outputs (covers out0+out1)
  hipMemsetAsync(out0, 0x7F, (size_t)8<<20, stream);

  dim3 blk(256);
  k_embed<<<1024, blk, 0, stream>>>(x, xp, we, pe, X0);

  k_gemm_abT<<<dim3(32,8), blk, 0, stream>>>(X0, Wih, pre, 1024, 4096, 1024, bl, nullptr);
  k_lstm_scan<<<SCAN_WGS+HEAT_WGS, dim3(512), 0, stream>>>(pre, Whh, out0, Wih);

  k_gemm_abT<<<dim3(32,8), blk, 0, stream>>>(out0, Wih + (size_t)4096*1024, pre,
                                             1024, 4096, 1024, bl + 4096, nullptr);
  k_lstm_scan<<<SCAN_WGS+HEAT_WGS, dim3(512), 0, stream>>>(pre, Whh + (size_t)2*2048*512, out1, Wih);

  k_gemm_hd <<<dim3(16,8), blk, 0, stream>>>(out1, Wh, bh, head, Wd, bd, dep);
  k_gemm_abT<<<dim3(8,8), blk, 0, stream>>>(dep,  Wbi, Ubuf,1024, 1024, 1024, nullptr, nullptr);
  k_gemm_abT<<<dim3(8,8), blk, 0, stream>>>(head, Ubuf, outp,1024, 1024, 1024, nullptr, bbi);

  k_softmax<<<1024, blk, 0, stream>>>(outp);
}